// Round 2
// baseline (342.648 us; speedup 1.0000x reference)
//
#include <hip/hip_runtime.h>

// VQ argmin, bit-replicating the numpy fp32 reference:
//   d[i,k] = fp32( fp32(A_i + B_k) - 2*M_ik )
//   A_i = np.sum(z_i*z_i)   (numpy pairwise order, fp32)
//   B_k = np.sum(c_k*c_k)   (numpy pairwise order, fp32)
//   M_ik = sgemm: ascending-k single-accumulator FMA chain (fp32)
// argmin with first-index tie-break.
// B=16 D=256 H=W=32 -> n=16384 pixels; K=2048 codes.

#define D_  256
#define K_  2048
#define HW_ 1024
#define MT  32     // pixels per block (vq_k)
#define NT  256    // codes per n-chunk
#define KT  32     // dims per k-chunk
#define CST 258    // cs row stride: even (b64 align), 2-way banks only (free)

// numpy pairwise combine of 8 accumulators:
// ((r0+r1)+(r2+r3)) + ((r4+r5)+(r6+r7)), exact fp32 adds
__device__ __forceinline__ float pw8(const float r[8]) {
    float t01 = __fadd_rn(r[0], r[1]);
    float t23 = __fadd_rn(r[2], r[3]);
    float L   = __fadd_rn(t01, t23);
    float t45 = __fadd_rn(r[4], r[5]);
    float t67 = __fadd_rn(r[6], r[7]);
    float R   = __fadd_rn(t45, t67);
    return __fadd_rn(L, R);
}

// B_k = pairwise sum of c_k^2: halves [0:128),[128:256), 8 accs r[j] += p[8t+j]
__global__ __launch_bounds__(256) void bn_k(const float* __restrict__ cb,
                                            float* __restrict__ Bn) {
    int row = blockIdx.x * 256 + threadIdx.x;      // grid = 8 -> 2048 rows
    const float4* p = reinterpret_cast<const float4*>(cb + (size_t)row * D_);
    float rA[8], rB[8];
    #pragma unroll
    for (int j = 0; j < 8; ++j) { rA[j] = 0.f; rB[j] = 0.f; }
    #pragma unroll
    for (int q = 0; q < 64; ++q) {                 // float4 q covers k=4q..4q+3
        float4 v = p[q];
        float pv[4] = {__fmul_rn(v.x, v.x), __fmul_rn(v.y, v.y),
                       __fmul_rn(v.z, v.z), __fmul_rn(v.w, v.w)};
        if (q < 32) {
            #pragma unroll
            for (int l = 0; l < 4; ++l) {
                int j = (4 * q + l) & 7;
                rA[j] = __fadd_rn(rA[j], pv[l]);
            }
        } else {
            #pragma unroll
            for (int l = 0; l < 4; ++l) {
                int j = (4 * q + l) & 7;
                rB[j] = __fadd_rn(rB[j], pv[l]);
            }
        }
    }
    Bn[row] = __fadd_rn(pw8(rA), pw8(rB));
}

// A_i per pixel, same pairwise order. Block: 256 pixels; LDS-staged coalesced.
__global__ __launch_bounds__(256) void an_k(const float* __restrict__ z,
                                            float* __restrict__ An) {
    __shared__ float ls[KT][256];                  // 32 KB
    int b      = blockIdx.x >> 2;                  // 64 blocks: 16 images x 4
    int hwbase = (blockIdx.x & 3) << 8;
    const float* zb = z + (size_t)b * (D_ * HW_) + hwbase;
    int tid = threadIdx.x;
    float rA[8], rB[8];
    #pragma unroll
    for (int j = 0; j < 8; ++j) { rA[j] = 0.f; rB[j] = 0.f; }
    for (int kc = 0; kc < 8; ++kc) {
        __syncthreads();
        #pragma unroll
        for (int it = 0; it < 8; ++it) {           // 2048 float4 = 256thr x 8
            int u  = (it << 8) + tid;
            int dd = u >> 6;                       // 0..31
            int m4 = u & 63;
            float4 v = *reinterpret_cast<const float4*>(
                zb + (size_t)(kc * KT + dd) * HW_ + (m4 << 2));
            *reinterpret_cast<float4*>(&ls[dd][m4 << 2]) = v;
        }
        __syncthreads();
        if (kc < 4) {
            #pragma unroll
            for (int dd = 0; dd < 32; ++dd) {      // k = kc*32+dd ascending
                float v = ls[dd][tid];
                rA[dd & 7] = __fadd_rn(rA[dd & 7], __fmul_rn(v, v));
            }
        } else {
            #pragma unroll
            for (int dd = 0; dd < 32; ++dd) {
                float v = ls[dd][tid];
                rB[dd & 7] = __fadd_rn(rB[dd & 7], __fmul_rn(v, v));
            }
        }
    }
    An[(size_t)b * HW_ + hwbase + tid] = __fadd_rn(pw8(rA), pw8(rB));
}

__global__ __launch_bounds__(256, 2) void vq_k(const float* __restrict__ z,
                                               const float* __restrict__ cb,
                                               const float* __restrict__ An,
                                               const float* __restrict__ Bn,
                                               float* __restrict__ out) {
    __shared__ float zs[KT][MT];        // [dim][pixel] 4 KB
    __shared__ float cs[KT * CST];      // [dim][code]  33 KB (transposed tile)
    __shared__ float rs[MT * 33];
    __shared__ int   ri[MT * 33];
    __shared__ int   idxs[MT];

    const int tid = threadIdx.x;
    const int tn  = tid & 31;           // 32 groups in code dir
    const int tm  = tid >> 5;           // 8 groups in pixel dir
    const int blk = blockIdx.x;
    const int b      = blk >> 5;        // 32 blocks per image
    const int hwbase = (blk & 31) << 5;
    const float* zbase = z + (size_t)b * (D_ * HW_) + hwbase;

    float an[4];
    #pragma unroll
    for (int i = 0; i < 4; ++i)
        an[i] = An[(size_t)b * HW_ + hwbase + (tm << 2) + i];

    float bs[4] = {1e30f, 1e30f, 1e30f, 1e30f};
    int   bi[4] = {0, 0, 0, 0};

    for (int nc = 0; nc < K_ / NT; ++nc) {
        float acc[4][8];
        #pragma unroll
        for (int i = 0; i < 4; ++i)
            #pragma unroll
            for (int j = 0; j < 8; ++j) acc[i][j] = 0.f;

        for (int kc = 0; kc < D_ / KT; ++kc) {
            __syncthreads();
            {   // stage z tile: 32 dims x 32 pixels, coalesced float4
                int dd = tid >> 3;
                int m4 = tid & 7;
                float4 v = *reinterpret_cast<const float4*>(
                    zbase + (size_t)(kc * KT + dd) * HW_ + (m4 << 2));
                *reinterpret_cast<float4*>(&zs[dd][m4 << 2]) = v;
            }
            {   // stage code tile transposed: 256 codes x 32 dims
                const float* cbase = cb + (size_t)(nc * NT) * D_ + kc * KT;
                #pragma unroll
                for (int it = 0; it < 8; ++it) {
                    int u  = (it << 8) + tid;
                    int nn = u >> 3;
                    int d4 = u & 7;
                    float4 v = *reinterpret_cast<const float4*>(
                        cbase + (size_t)nn * D_ + (d4 << 2));
                    int db = d4 << 2;
                    cs[(db + 0) * CST + nn] = v.x;
                    cs[(db + 1) * CST + nn] = v.y;
                    cs[(db + 2) * CST + nn] = v.z;
                    cs[(db + 3) * CST + nn] = v.w;
                }
            }
            __syncthreads();
            // ascending-k FMA chain per (pixel, code) — bit-matches sgemm
            #pragma unroll
            for (int d = 0; d < KT; ++d) {
                float4 a = *reinterpret_cast<const float4*>(&zs[d][tm << 2]);
                const float* crow = &cs[d * CST + (tn << 1)];
                float2 b0 = *reinterpret_cast<const float2*>(crow);
                float2 b1 = *reinterpret_cast<const float2*>(crow + 64);
                float2 b2 = *reinterpret_cast<const float2*>(crow + 128);
                float2 b3 = *reinterpret_cast<const float2*>(crow + 192);
                float av[4] = {a.x, a.y, a.z, a.w};
                float bv[8] = {b0.x, b0.y, b1.x, b1.y, b2.x, b2.y, b3.x, b3.y};
                #pragma unroll
                for (int i = 0; i < 4; ++i)
                    #pragma unroll
                    for (int j = 0; j < 8; ++j)
                        acc[i][j] = fmaf(av[i], bv[j], acc[i][j]);
            }
        }
        // fold: d = fp32( fp32(A+B) - 2*M ), ascending code index per thread
        #pragma unroll
        for (int j = 0; j < 8; ++j) {
            int nl = (j & 1) + (tn << 1) + ((j >> 1) << 6);
            int ng = nc * NT + nl;
            float bn = Bn[ng];
            #pragma unroll
            for (int i = 0; i < 4; ++i) {
                float sc = __fsub_rn(__fadd_rn(an[i], bn),
                                     __fmul_rn(2.0f, acc[i][j]));
                if (sc < bs[i]) { bs[i] = sc; bi[i] = ng; }
            }
        }
    }

    // cross-thread reduce over the 32 tn-groups per pixel (first-min tiebreak)
    #pragma unroll
    for (int i = 0; i < 4; ++i) {
        int m = (tm << 2) + i;
        rs[m * 33 + tn] = bs[i];
        ri[m * 33 + tn] = bi[i];
    }
    __syncthreads();
    if (tid < MT) {
        int   m    = tid;
        float best = rs[m * 33];
        int   bidx = ri[m * 33];
        for (int t = 1; t < 32; ++t) {
            float s  = rs[m * 33 + t];
            int   ix = ri[m * 33 + t];
            if (s < best || (s == best && ix < bidx)) { best = s; bidx = ix; }
        }
        idxs[m] = bidx;
    }
    __syncthreads();

    // fused gather-output: out[b][d][hwbase+m] = cb[idx[m]][d]
    float* obase = out + (size_t)b * (D_ * HW_) + hwbase;
    #pragma unroll
    for (int it = 0; it < 8; ++it) {
        int u  = (it << 8) + tid;
        int dd = u >> 3;
        int m4 = u & 7;
        int i0 = idxs[(m4 << 2) + 0];
        int i1 = idxs[(m4 << 2) + 1];
        int i2 = idxs[(m4 << 2) + 2];
        int i3 = idxs[(m4 << 2) + 3];
        float4 o;
        o.x = cb[(size_t)i0 * D_ + dd];
        o.y = cb[(size_t)i1 * D_ + dd];
        o.z = cb[(size_t)i2 * D_ + dd];
        o.w = cb[(size_t)i3 * D_ + dd];
        *reinterpret_cast<float4*>(obase + (size_t)dd * HW_ + (m4 << 2)) = o;
    }
}

extern "C" void kernel_launch(void* const* d_in, const int* in_sizes, int n_in,
                              void* d_out, int out_size, void* d_ws, size_t ws_size,
                              hipStream_t stream) {
    const float* z  = (const float*)d_in[0];   // 16*256*32*32
    const float* cb = (const float*)d_in[1];   // 2048*256
    float* An = (float*)d_ws;                  // 16384 floats
    float* Bn = (float*)d_ws + 16384;          // 2048 floats
    float* out = (float*)d_out;

    bn_k<<<dim3(K_ / 256), dim3(256), 0, stream>>>(cb, Bn);
    an_k<<<dim3(64), dim3(256), 0, stream>>>(z, An);
    vq_k<<<dim3(16384 / MT), dim3(256), 0, stream>>>(z, cb, An, Bn, out);
}